// Round 2
// baseline (2682.881 us; speedup 1.0000x reference)
//
#include <hip/hip_runtime.h>

// ReservoirLayer: S0 = pad(x,[2048,4096]); 16x: S = leaky_relu(S @ W, 0.1)
// Strategy: fp32-emulation via fp16 hi/lo split (fp16x3), MFMA GEMM.
//   W' = 256*W split into fp16 (hi,lo), pre-transposed to [n][k] for B-frag loads.
//   S split into fp16 (hi,lo) each step in the GEMM epilogue.
//   acc = Sh@Wh + Sl@Wh + Sh@Wl (fp32 accum), g = acc/256, s = leaky(g).
// R2: LDS double-buffer (1 barrier/iter, prefetch overlaps compute) +
//     XCD-aware block swizzle (8x8 region per XCD -> k-slice reuse in 4MB L2).

#define BATCH 2048
#define NDIM  4096
#define INDIM 512
#define BM 128
#define BN 128
#define BK 32

typedef _Float16 f16x8 __attribute__((ext_vector_type(8)));
typedef float    f32x4 __attribute__((ext_vector_type(4)));

__device__ __forceinline__ void async16(const void* gsrc, void* ldst) {
  const __attribute__((address_space(1))) unsigned int* g =
      (const __attribute__((address_space(1))) unsigned int*)gsrc;
  __attribute__((address_space(3))) unsigned int* l =
      (__attribute__((address_space(3))) unsigned int*)ldst;
  __builtin_amdgcn_global_load_lds(g, l, 16, 0, 0);
}

// read one 16B fragment (8 halves) from an LDS tile [128][32] with k-chunk swizzle:
// LDS chunk c holds global k-chunk c ^ ((row>>1)&3)
__device__ __forceinline__ f16x8 frag(const _Float16* s, int row, int q) {
  int ch = q ^ ((row >> 1) & 3);
  return *(const f16x8*)(s + row * BK + ch * 8);
}

// ---------------- prep: split+pad x into S_hi/S_lo ----------------
__global__ void prep_x(const float* __restrict__ x,
                       _Float16* __restrict__ Sh, _Float16* __restrict__ Sl) {
  size_t i = (size_t)blockIdx.x * 256 + threadIdx.x;  // over BATCH*NDIM
  int b = (int)(i >> 12);
  int n = (int)(i & (NDIM - 1));
  float v = (n < INDIM) ? x[(size_t)b * INDIM + n] : 0.0f;
  _Float16 h = (_Float16)v;
  Sh[i] = h;
  Sl[i] = (_Float16)(v - (float)h);
}

// ---------------- prep: transpose + scale(256) + split W ----------------
// W[k][n] fp32 -> Wt_hi/Wt_lo [n][k] fp16
__global__ void prep_w(const float* __restrict__ W,
                       _Float16* __restrict__ Wth, _Float16* __restrict__ Wtl) {
  __shared__ float tile[32][33];
  int k0 = blockIdx.y * 32, n0 = blockIdx.x * 32;
  int tx = threadIdx.x, ty = threadIdx.y;  // 32 x 8
  for (int r = 0; r < 4; r++) {
    int k = k0 + ty + r * 8;
    tile[ty + r * 8][tx] = W[(size_t)k * NDIM + n0 + tx];
  }
  __syncthreads();
  for (int r = 0; r < 4; r++) {
    int n = n0 + ty + r * 8;
    float v = tile[tx][ty + r * 8] * 256.0f;
    _Float16 h = (_Float16)v;
    Wth[(size_t)n * NDIM + k0 + tx] = h;
    Wtl[(size_t)n * NDIM + k0 + tx] = (_Float16)(v - (float)h);
  }
}

// ---------------- one recurrence step ----------------
// MODE 0: write split fp16 next-state; MODE 1: write fp32 to d_out
template <int MODE>
__global__ __launch_bounds__(256, 2) void step_kernel(
    const _Float16* __restrict__ Ah, const _Float16* __restrict__ Al,
    const _Float16* __restrict__ Bh, const _Float16* __restrict__ Bl,
    _Float16* __restrict__ Dh, _Float16* __restrict__ Dl,
    float* __restrict__ Dout, int k_len) {
  __shared__ _Float16 sAh[2][BM * BK];
  __shared__ _Float16 sAl[2][BM * BK];
  __shared__ _Float16 sBh[2][BN * BK];
  __shared__ _Float16 sBl[2][BN * BK];

  const int tid = threadIdx.x;
  const int lane = tid & 63;
  const int w = tid >> 6;          // wave 0..3
  const int wm = w >> 1;           // 2x2 wave grid
  const int wn = w & 1;

  // XCD-aware swizzle: 512 blocks, round-robin dispatch -> xcd = id & 7.
  // Each XCD owns an 8x8 region of the 16(row) x 32(col) block grid so its
  // 64 co-resident blocks share A-row/B-col k-slices through the 4MB L2.
  int id = blockIdx.x;
  int xcd = id & 7;
  int local = id >> 3;             // 0..63
  int lr = local & 7;              // row in region
  int lc = local >> 3;             // col in region
  int rb = (xcd & 1) * 8 + lr;     // 0..15
  int cb = (xcd >> 1) * 8 + lc;    // 0..31
  const int bm = rb * BM;          // batch rows
  const int bn = cb * BN;          // output cols

  const int sr = lane >> 2;        // staging: row-in-16 group
  const int cl = lane & 3;         // staging: lds chunk
  const int fm = lane & 15;        // frag row/col within 16-tile
  const int fq = lane >> 4;        // frag k-quad

  f32x4 acc[4][4];
  for (int i = 0; i < 4; i++)
    for (int j = 0; j < 4; j++) acc[i][j] = (f32x4){0.f, 0.f, 0.f, 0.f};

  auto stage = [&](int kt, int buf) {
    for (int q = 0; q < 2; q++) {
      int t = w * 2 + q;
      int r = t * 16 + sr;                 // 0..127
      int cg = cl ^ ((r >> 1) & 3);        // global k-chunk for this lds slot
      size_t goA = (size_t)(bm + r) * NDIM + kt + cg * 8;
      size_t goB = (size_t)(bn + r) * NDIM + kt + cg * 8;
      int lo = r * BK + cl * 8;
      async16(Ah + goA, &sAh[buf][lo]);
      async16(Al + goA, &sAl[buf][lo]);
      async16(Bh + goB, &sBh[buf][lo]);
      async16(Bl + goB, &sBl[buf][lo]);
    }
  };

  stage(0, 0);
  asm volatile("s_waitcnt vmcnt(0)" ::: "memory");
  __syncthreads();

  const int nk = k_len / BK;
  for (int it = 0; it < nk; it++) {
    const int cur = it & 1;
    if (it + 1 < nk) stage((it + 1) * BK, cur ^ 1);  // prefetch, no wait

    // ---- fragments + MFMA from buf `cur`
    f16x8 ah[4], al[4];
    for (int i = 0; i < 4; i++) {
      int r = wm * 64 + i * 16 + fm;
      ah[i] = frag(sAh[cur], r, fq);
      al[i] = frag(sAl[cur], r, fq);
    }
    for (int j = 0; j < 4; j++) {
      int r = wn * 64 + j * 16 + fm;
      f16x8 bh = frag(sBh[cur], r, fq);
      f16x8 bl = frag(sBl[cur], r, fq);
      for (int i = 0; i < 4; i++) {
        acc[i][j] = __builtin_amdgcn_mfma_f32_16x16x32_f16(ah[i], bh, acc[i][j], 0, 0, 0);
        acc[i][j] = __builtin_amdgcn_mfma_f32_16x16x32_f16(al[i], bh, acc[i][j], 0, 0, 0);
        acc[i][j] = __builtin_amdgcn_mfma_f32_16x16x32_f16(ah[i], bl, acc[i][j], 0, 0, 0);
      }
    }

    // drain this iter's prefetch (overlapped with the MFMAs above), then
    // one barrier: protects both buf reuse and prefetch visibility.
    asm volatile("s_waitcnt vmcnt(0)" ::: "memory");
    __syncthreads();
  }

  // ---- epilogue: undo 256x W-scale, leaky relu, write next state / output
  const float inv = 1.0f / 256.0f;
  for (int i = 0; i < 4; i++) {
    for (int j = 0; j < 4; j++) {
      for (int e = 0; e < 4; e++) {
        int r = bm + wm * 64 + i * 16 + fq * 4 + e;   // C/D: row=(lane>>4)*4+reg
        int c = bn + wn * 64 + j * 16 + fm;           //      col=lane&15
        float g = acc[i][j][e] * inv;
        float s = (g > 0.0f) ? g : 0.1f * g;
        if (MODE == 0) {
          _Float16 h = (_Float16)s;
          Dh[(size_t)r * NDIM + c] = h;
          Dl[(size_t)r * NDIM + c] = (_Float16)(s - (float)h);
        } else {
          Dout[(size_t)r * NDIM + c] = s;
        }
      }
    }
  }
}

extern "C" void kernel_launch(void* const* d_in, const int* in_sizes, int n_in,
                              void* d_out, int out_size, void* d_ws, size_t ws_size,
                              hipStream_t stream) {
  const float* x = (const float*)d_in[0];   // [2048, 512]
  const float* W = (const float*)d_in[1];   // [4096, 4096]
  float* out = (float*)d_out;               // [2048, 4096]
  char* ws = (char*)d_ws;

  const size_t WT_BYTES = (size_t)NDIM * NDIM * 2;   // 32 MB each
  const size_t S_BYTES = (size_t)BATCH * NDIM * 2;   // 16 MB each
  _Float16* Wth = (_Float16*)ws;
  _Float16* Wtl = (_Float16*)(ws + WT_BYTES);
  _Float16* SAh = (_Float16*)(ws + 2 * WT_BYTES);
  _Float16* SAl = (_Float16*)(ws + 2 * WT_BYTES + S_BYTES);
  _Float16* SBh = (_Float16*)(ws + 2 * WT_BYTES + 2 * S_BYTES);
  _Float16* SBl = (_Float16*)(ws + 2 * WT_BYTES + 3 * S_BYTES);

  prep_x<<<(BATCH * NDIM) / 256, 256, 0, stream>>>(x, SAh, SAl);
  prep_w<<<dim3(NDIM / 32, NDIM / 32), dim3(32, 8), 0, stream>>>(W, Wth, Wtl);

  dim3 grid((NDIM / BN) * (BATCH / BM));  // 512 linear, swizzled in-kernel
  for (int t = 1; t <= 16; t++) {
    const _Float16* ah = (t & 1) ? SAh : SBh;
    const _Float16* al = (t & 1) ? SAl : SBl;
    _Float16* dh = (t & 1) ? SBh : SAh;
    _Float16* dl = (t & 1) ? SBl : SAl;
    int klen = (t == 1) ? INDIM : NDIM;
    if (t < 16)
      step_kernel<0><<<grid, 256, 0, stream>>>(ah, al, Wth, Wtl, dh, dl, nullptr, klen);
    else
      step_kernel<1><<<grid, 256, 0, stream>>>(ah, al, Wth, Wtl, nullptr, nullptr, out, klen);
  }
}

// Round 3
// 2414.633 us; speedup vs baseline: 1.1111x; 1.1111x over previous
//
#include <hip/hip_runtime.h>

// ReservoirLayer: S0 = pad(x,[2048,4096]); 16x: S = leaky_relu(S @ W, 0.1)
// fp32-emulation via fp16 hi/lo split (fp16x3): acc = Sh@Wh + Sl@Wh + Sh@Wl.
// R3: depth-2 software pipeline — frag reads lead MFMAs by 1 iter (two register
// frag sets), staging leads by 2 iters. The barrier's vmcnt(0) drain only ever
// waits on a stage issued one full iteration earlier -> no stall; ds_read burst
// overlaps the previous iteration's MFMA block.

#define BATCH 2048
#define NDIM  4096
#define INDIM 512
#define BM 128
#define BN 128
#define BK 32

typedef _Float16 f16x8 __attribute__((ext_vector_type(8)));
typedef float    f32x4 __attribute__((ext_vector_type(4)));

__device__ __forceinline__ void async16(const void* gsrc, void* ldst) {
  const __attribute__((address_space(1))) unsigned int* g =
      (const __attribute__((address_space(1))) unsigned int*)gsrc;
  __attribute__((address_space(3))) unsigned int* l =
      (__attribute__((address_space(3))) unsigned int*)ldst;
  __builtin_amdgcn_global_load_lds(g, l, 16, 0, 0);
}

// ---------------- prep: split+pad x into S_hi/S_lo ----------------
__global__ void prep_x(const float* __restrict__ x,
                       _Float16* __restrict__ Sh, _Float16* __restrict__ Sl) {
  size_t i = (size_t)blockIdx.x * 256 + threadIdx.x;  // over BATCH*NDIM
  int b = (int)(i >> 12);
  int n = (int)(i & (NDIM - 1));
  float v = (n < INDIM) ? x[(size_t)b * INDIM + n] : 0.0f;
  _Float16 h = (_Float16)v;
  Sh[i] = h;
  Sl[i] = (_Float16)(v - (float)h);
}

// ---------------- prep: transpose + scale(256) + split W ----------------
__global__ void prep_w(const float* __restrict__ W,
                       _Float16* __restrict__ Wth, _Float16* __restrict__ Wtl) {
  __shared__ float tile[32][33];
  int k0 = blockIdx.y * 32, n0 = blockIdx.x * 32;
  int tx = threadIdx.x, ty = threadIdx.y;  // 32 x 8
  for (int r = 0; r < 4; r++) {
    int k = k0 + ty + r * 8;
    tile[ty + r * 8][tx] = W[(size_t)k * NDIM + n0 + tx];
  }
  __syncthreads();
  for (int r = 0; r < 4; r++) {
    int n = n0 + ty + r * 8;
    float v = tile[tx][ty + r * 8] * 256.0f;
    _Float16 h = (_Float16)v;
    Wth[(size_t)n * NDIM + k0 + tx] = h;
    Wtl[(size_t)n * NDIM + k0 + tx] = (_Float16)(v - (float)h);
  }
}

// read one frag set from LDS buffers b (compile-time 0/1 at all call sites)
#define READF(b, A, L, Bv, M)                          \
  do {                                                 \
    _Pragma("unroll") for (int i = 0; i < 4; i++) {    \
      A[i]  = *(const f16x8*)&sAh[b][oA[i]];           \
      L[i]  = *(const f16x8*)&sAl[b][oA[i]];           \
      Bv[i] = *(const f16x8*)&sBh[b][oB[i]];           \
      M[i]  = *(const f16x8*)&sBl[b][oB[i]];           \
    }                                                  \
  } while (0)

#define MFMAS(A, L, Bv, M)                                                          \
  do {                                                                              \
    _Pragma("unroll") for (int j = 0; j < 4; j++)                                   \
    _Pragma("unroll") for (int i = 0; i < 4; i++) {                                 \
      acc[i][j] = __builtin_amdgcn_mfma_f32_16x16x32_f16(A[i], Bv[j], acc[i][j], 0, 0, 0); \
      acc[i][j] = __builtin_amdgcn_mfma_f32_16x16x32_f16(L[i], Bv[j], acc[i][j], 0, 0, 0); \
      acc[i][j] = __builtin_amdgcn_mfma_f32_16x16x32_f16(A[i], M[j], acc[i][j], 0, 0, 0); \
    }                                                                               \
  } while (0)

// ---------------- one recurrence step ----------------
template <int MODE>
__global__ __launch_bounds__(256, 2) void step_kernel(
    const _Float16* __restrict__ Ah, const _Float16* __restrict__ Al,
    const _Float16* __restrict__ Bh, const _Float16* __restrict__ Bl,
    _Float16* __restrict__ Dh, _Float16* __restrict__ Dl,
    float* __restrict__ Dout, int k_len) {
  __shared__ _Float16 sAh[2][BM * BK];
  __shared__ _Float16 sAl[2][BM * BK];
  __shared__ _Float16 sBh[2][BN * BK];
  __shared__ _Float16 sBl[2][BN * BK];

  const int tid = threadIdx.x;
  const int lane = tid & 63;
  const int w = tid >> 6;
  const int wm = w >> 1, wn = w & 1;

  // XCD-aware swizzle: 8x8 block region per XCD (round-robin dispatch, id&7)
  int id = blockIdx.x;
  int xcd = id & 7, local = id >> 3;
  int lr = local & 7, lc = local >> 3;
  const int bm = ((xcd & 1) * 8 + lr) * BM;
  const int bn = ((xcd >> 1) * 8 + lc) * BN;

  const int sr = lane >> 2, cl = lane & 3;
  const int fm = lane & 15, fq = lane >> 4;

  // loop-invariant LDS fragment element-offsets (k-chunk swizzled)
  int oA[4], oB[4];
#pragma unroll
  for (int i = 0; i < 4; i++) {
    int rA = wm * 64 + i * 16 + fm;
    oA[i] = rA * BK + (fq ^ ((rA >> 1) & 3)) * 8;
    int rB = wn * 64 + i * 16 + fm;
    oB[i] = rB * BK + (fq ^ ((rB >> 1) & 3)) * 8;
  }

  // loop-invariant staging addresses (k added per call)
  int r0 = w * 32 + sr, r1 = r0 + 16;
  int cg0 = cl ^ ((r0 >> 1) & 3);
  int cg1 = cl ^ ((r1 >> 1) & 3);
  const size_t gA0 = (size_t)(bm + r0) * NDIM + cg0 * 8;
  const size_t gA1 = (size_t)(bm + r1) * NDIM + cg1 * 8;
  const size_t gB0 = (size_t)(bn + r0) * NDIM + cg0 * 8;
  const size_t gB1 = (size_t)(bn + r1) * NDIM + cg1 * 8;
  const int lo0 = r0 * BK + cl * 8;
  const int lo1 = r1 * BK + cl * 8;

  auto stage = [&](int kt, int b) {
    async16(Ah + gA0 + kt, &sAh[b][lo0]);
    async16(Ah + gA1 + kt, &sAh[b][lo1]);
    async16(Al + gA0 + kt, &sAl[b][lo0]);
    async16(Al + gA1 + kt, &sAl[b][lo1]);
    async16(Bh + gB0 + kt, &sBh[b][lo0]);
    async16(Bh + gB1 + kt, &sBh[b][lo1]);
    async16(Bl + gB0 + kt, &sBl[b][lo0]);
    async16(Bl + gB1 + kt, &sBl[b][lo1]);
  };

  f32x4 acc[4][4];
#pragma unroll
  for (int i = 0; i < 4; i++)
#pragma unroll
    for (int j = 0; j < 4; j++) acc[i][j] = (f32x4){0.f, 0.f, 0.f, 0.f};

  f16x8 a0[4], l0[4], b0[4], m0[4];  // frag set 0
  f16x8 a1[4], l1[4], b1[4], m1[4];  // frag set 1

  const int nk = k_len / BK;  // 16 or 128 (even)

  // prologue
  stage(0 * BK, 0);
  stage(1 * BK, 1);
  __syncthreads();               // tiles 0,1 staged (one-time drain)
  READF(0, a0, l0, b0, m0);
  __syncthreads();               // reads(0) drained -> buf0 reusable
  stage(2 * BK, 0);

  // main: READF(it) | MFMA(it-1) | sync | stage(it+2)
  int it = 1;
  for (; it + 1 < nk; it += 2) {
    READF(1, a1, l1, b1, m1);    // reads(it), it odd -> buf1
    MFMAS(a0, l0, b0, m0);       // MFMA(it-1)
    __syncthreads();
    if (it + 2 < nk) stage((it + 2) * BK, 1);

    READF(0, a0, l0, b0, m0);    // reads(it+1), even -> buf0
    MFMAS(a1, l1, b1, m1);       // MFMA(it)
    __syncthreads();
    if (it + 3 < nk) stage((it + 3) * BK, 0);
  }
  // tail: it == nk-1 (odd)
  READF(1, a1, l1, b1, m1);      // reads(nk-1)
  MFMAS(a0, l0, b0, m0);         // MFMA(nk-2)
  MFMAS(a1, l1, b1, m1);         // MFMA(nk-1) — lgkmcnt dep handled by compiler

  // ---- epilogue: undo 256x W-scale, leaky relu, write next state / output
  const float inv = 1.0f / 256.0f;
#pragma unroll
  for (int i = 0; i < 4; i++) {
#pragma unroll
    for (int j = 0; j < 4; j++) {
#pragma unroll
      for (int e = 0; e < 4; e++) {
        int r = bm + wm * 64 + i * 16 + fq * 4 + e;  // C/D: row=(lane>>4)*4+reg
        int c = bn + wn * 64 + j * 16 + fm;          //      col=lane&15
        float g = acc[i][j][e] * inv;
        float s = (g > 0.0f) ? g : 0.1f * g;
        if (MODE == 0) {
          _Float16 h = (_Float16)s;
          Dh[(size_t)r * NDIM + c] = h;
          Dl[(size_t)r * NDIM + c] = (_Float16)(s - (float)h);
        } else {
          Dout[(size_t)r * NDIM + c] = s;
        }
      }
    }
  }
}

extern "C" void kernel_launch(void* const* d_in, const int* in_sizes, int n_in,
                              void* d_out, int out_size, void* d_ws, size_t ws_size,
                              hipStream_t stream) {
  const float* x = (const float*)d_in[0];  // [2048, 512]
  const float* W = (const float*)d_in[1];  // [4096, 4096]
  float* out = (float*)d_out;              // [2048, 4096]
  char* ws = (char*)d_ws;

  const size_t WT_BYTES = (size_t)NDIM * NDIM * 2;  // 32 MB each
  const size_t S_BYTES = (size_t)BATCH * NDIM * 2;  // 16 MB each
  _Float16* Wth = (_Float16*)ws;
  _Float16* Wtl = (_Float16*)(ws + WT_BYTES);
  _Float16* SAh = (_Float16*)(ws + 2 * WT_BYTES);
  _Float16* SAl = (_Float16*)(ws + 2 * WT_BYTES + S_BYTES);
  _Float16* SBh = (_Float16*)(ws + 2 * WT_BYTES + 2 * S_BYTES);
  _Float16* SBl = (_Float16*)(ws + 2 * WT_BYTES + 3 * S_BYTES);

  prep_x<<<(BATCH * NDIM) / 256, 256, 0, stream>>>(x, SAh, SAl);
  prep_w<<<dim3(NDIM / 32, NDIM / 32), dim3(32, 8), 0, stream>>>(W, Wth, Wtl);

  dim3 grid((NDIM / BN) * (BATCH / BM));  // 512 linear, swizzled in-kernel
  for (int t = 1; t <= 16; t++) {
    const _Float16* ah = (t & 1) ? SAh : SBh;
    const _Float16* al = (t & 1) ? SAl : SBl;
    _Float16* dh = (t & 1) ? SBh : SAh;
    _Float16* dl = (t & 1) ? SBl : SAl;
    int klen = (t == 1) ? INDIM : NDIM;
    if (t < 16)
      step_kernel<0><<<grid, 256, 0, stream>>>(ah, al, Wth, Wtl, dh, dl, nullptr, klen);
    else
      step_kernel<1><<<grid, 256, 0, stream>>>(ah, al, Wth, Wtl, nullptr, nullptr, out, klen);
  }
}